// Round 3
// baseline (2415.706 us; speedup 1.0000x reference)
//
#include <hip/hip_runtime.h>
#include <hip/hip_bf16.h>
#include <stdint.h>

// MoE FFN: T=8192 tokens, DIM=1024, HID=2752, E=8, K=2 + shared expert.
// Device I/O dtype is ambiguous (reference is f32; harness may deliver bf16).
// k_detect probes x's bit patterns and sets mode: 0 = bf16 buffers, 1 = f32
// buffers. All loads of x/weights and the final store branch on mode
// (wave-uniform). Internal compute: bf16 MFMA GEMMs, fp32 accumulation.
//
// Pipeline: detect -> init -> gate -> scan -> scatter ->
//   phase S: up(shared) -> down(shared, plain store to zeroed out_acc)
//   phase R: up(routed)  -> down(routed, fp32 atomicAdd)
// -> combine (fp32 -> mode dtype).

#define T_TOK 8192
#define DIM   1024
#define HID   2752
#define NE    8
#define BM    128
#define BK    64
#define MAXROUTED   17408
#define MAXROUTEDMT 136

typedef short  s8v  __attribute__((ext_vector_type(8)));
typedef short  s4v  __attribute__((ext_vector_type(4)));
typedef float  f4v  __attribute__((ext_vector_type(4)));
typedef unsigned short u16;

__device__ __forceinline__ float b2f(u16 u) {
    union { unsigned int i; float f; } v; v.i = ((unsigned int)u) << 16; return v.f;
}
__device__ __forceinline__ u16 f2b(float f) {
    union { float f; unsigned int i; } v; v.f = f;
    unsigned int u = v.i;
    return (u16)((u + 0x7fffu + ((u >> 16) & 1u)) >> 16);   // RNE
}

// load 8 consecutive elements (bf16 bits) from base+elem_off, either dtype
__device__ __forceinline__ s8v load8(const void* base, size_t elem_off, int mode) {
    if (mode == 0) {
        return *(const s8v*)((const u16*)base + elem_off);
    } else {
        const float* f = (const float*)base + elem_off;
        f4v a = *(const f4v*)f;
        f4v b = *(const f4v*)(f + 4);
        s8v r;
        r[0] = (short)f2b(a[0]); r[1] = (short)f2b(a[1]);
        r[2] = (short)f2b(a[2]); r[3] = (short)f2b(a[3]);
        r[4] = (short)f2b(b[0]); r[5] = (short)f2b(b[1]);
        r[6] = (short)f2b(b[2]); r[7] = (short)f2b(b[3]);
        return r;
    }
}

// ---------------- dtype detect: bf16-NaN bit patterns in x ----------------
__global__ void k_detect(const u16* __restrict__ x, int* __restrict__ mode) {
    __shared__ int cnt;
    if (threadIdx.x == 0) cnt = 0;
    __syncthreads();
    int c = 0;
    for (int i = 0; i < 64; ++i) {
        u16 w = x[threadIdx.x * 64 + i];             // 16384-word sample
        if (((w >> 7) & 0xFF) == 0xFF) ++c;          // bf16 exp field all-ones
    }
    atomicAdd(&cnt, c);
    __syncthreads();
    if (threadIdx.x == 0) *mode = (cnt > 4) ? 1 : 0; // f32 sample ~32 hits, bf16 ~0
}

// ---------------- init: zero counts + out_acc, poison pair_tok ----------------
__global__ __launch_bounds__(256) void k_init(int* counts, int* pair_tok, float* out_acc) {
    int i = blockIdx.x * 256 + threadIdx.x;          // grid 8192
    if (i < NE) counts[i] = 0;
    if (i < MAXROUTED) pair_tok[i] = -1;
    *(f4v*)(out_acc + (size_t)i * 4) = (f4v)0.f;     // 8,388,608 floats exactly
}

// ---------------- gate: one wave per token ----------------
__global__ __launch_bounds__(256) void k_gate(const void* __restrict__ x, const void* __restrict__ gw,
                                              int* __restrict__ tok_e, float* __restrict__ tok_w,
                                              int* __restrict__ counts, const int* __restrict__ modep) {
    int mode = *modep;
    int tid  = blockIdx.x * 256 + threadIdx.x;
    int t    = tid >> 6;
    int lane = tid & 63;
    size_t xo = (size_t)t * DIM + lane * 16;
    float xv[16];
    if (mode == 0) {
        s8v a = *(const s8v*)((const u16*)x + xo);
        s8v b = *(const s8v*)((const u16*)x + xo + 8);
#pragma unroll
        for (int j = 0; j < 8; ++j) { xv[j] = b2f((u16)a[j]); xv[8 + j] = b2f((u16)b[j]); }
    } else {
        const float* f = (const float*)x + xo;
#pragma unroll
        for (int j = 0; j < 16; ++j) xv[j] = f[j];
    }
    float acc[NE];
#pragma unroll
    for (int e = 0; e < NE; ++e) {
        size_t go = (size_t)e * DIM + lane * 16;
        float gv[16];
        if (mode == 0) {
            s8v a = *(const s8v*)((const u16*)gw + go);
            s8v b = *(const s8v*)((const u16*)gw + go + 8);
#pragma unroll
            for (int j = 0; j < 8; ++j) { gv[j] = b2f((u16)a[j]); gv[8 + j] = b2f((u16)b[j]); }
        } else {
            const float* f = (const float*)gw + go;
#pragma unroll
            for (int j = 0; j < 16; ++j) gv[j] = f[j];
        }
        float s = 0.f;
#pragma unroll
        for (int j = 0; j < 16; ++j) s += xv[j] * gv[j];
        acc[e] = s;
    }
#pragma unroll
    for (int m = 32; m >= 1; m >>= 1) {
#pragma unroll
        for (int e = 0; e < NE; ++e) acc[e] += __shfl_xor(acc[e], m);
    }
    if (lane == 0) {
        int e0 = 0;
#pragma unroll
        for (int e = 1; e < NE; ++e) if (acc[e] > acc[e0]) e0 = e;
        int e1 = (e0 == 0) ? 1 : 0;
#pragma unroll
        for (int e = 0; e < NE; ++e) if (e != e0 && acc[e] > acc[e1]) e1 = e;
        float w0 = 1.f / (1.f + __expf(acc[e1] - acc[e0]));  // == renormalized top-2 softmax
        float w1 = 1.f - w0;
        tok_e[2 * t]     = e0;  tok_e[2 * t + 1] = e1;
        tok_w[2 * t]     = w0;  tok_w[2 * t + 1] = w1;
        atomicAdd(&counts[e0], 1);
        atomicAdd(&counts[e1], 1);
    }
}

// ---------------- scan ----------------
__global__ void k_scan(const int* __restrict__ counts, int* __restrict__ aoff, int* __restrict__ cursor) {
    if (threadIdx.x == 0) {
        int off = 0;
        for (int e = 0; e < NE; ++e) {
            aoff[e] = off; cursor[e] = off;
            off += (counts[e] + BM - 1) & ~(BM - 1);
        }
        aoff[NE] = off;
    }
}

// ---------------- scatter ----------------
__global__ __launch_bounds__(256) void k_scatter(const int* __restrict__ tok_e, const float* __restrict__ tok_w,
                                                 int* __restrict__ cursor,
                                                 int* __restrict__ pair_tok, float* __restrict__ pair_coef) {
    int t = blockIdx.x * 256 + threadIdx.x;   // grid 32
    if (t >= T_TOK) return;
#pragma unroll
    for (int k = 0; k < 2; ++k) {
        int e   = tok_e[2 * t + k];
        float w = tok_w[2 * t + k];
        int pos = atomicAdd(&cursor[e], 1);
        pair_tok[pos]  = t;
        pair_coef[pos] = w;
    }
}

// ---------------- stage 1: H = silu(x@W1^T) * (x@W3^T) ----------------
__global__ __launch_bounds__(256) void k_ffn_up(
    const void* __restrict__ x, const void* __restrict__ w1, const void* __restrict__ w3,
    const void* __restrict__ sw1, const void* __restrict__ sw3,
    const int* __restrict__ pair_tok, const int* __restrict__ aoff,
    u16* __restrict__ H, int isShared, const int* __restrict__ modep) {
    __shared__ alignas(16) u16 As [BM * BK];
    __shared__ alignas(16) u16 B1s[64 * BK];
    __shared__ alignas(16) u16 B3s[64 * BK];

    int mode = *modep;
    int m0 = blockIdx.x * BM;
    const void *W1, *W3;
    size_t eoff = 0;
    if (isShared) { W1 = sw1; W3 = sw3; }
    else {
        int ss = aoff[NE];
        if (m0 >= ss) return;
        int e = 0;
        for (int i = 1; i < NE; ++i) if (m0 >= aoff[i]) e = i;
        W1 = w1; W3 = w3; eoff = (size_t)e * HID * DIM;
    }
    int n0 = blockIdx.y * 64;

    int tid = threadIdx.x, wv = tid >> 6, lane = tid & 63;
    int wm = wv >> 1, wn = wv & 1;
    int r16 = lane & 15, kq = lane >> 4;

    size_t aOff[2];
#pragma unroll
    for (int i = 0; i < 2; ++i) {
        int row = m0 + (wv * 2 + i) * 16 + r16;
        int tok = isShared ? row : pair_tok[row];
        if (tok < 0) tok = 0;
        aOff[i] = (size_t)tok * DIM + kq * 8;
    }
    size_t bOff = eoff + (size_t)(n0 + wv * 16 + r16) * DIM + kq * 8;
    u16* lA0 = As  + (wv * 2 + 0) * 2 * 512 + lane * 8;
    u16* lA1 = As  + (wv * 2 + 1) * 2 * 512 + lane * 8;
    u16* lB1 = B1s + wv * 2 * 512 + lane * 8;
    u16* lB3 = B3s + wv * 2 * 512 + lane * 8;

    f4v acc1[4][2], acc3[4][2];
#pragma unroll
    for (int a = 0; a < 4; ++a)
#pragma unroll
        for (int b = 0; b < 2; ++b) { acc1[a][b] = (f4v)0.f; acc3[a][b] = (f4v)0.f; }

    for (int kt = 0; kt < DIM / BK; ++kt) {   // 16 iters
        int k0 = kt * BK;
        s8v rA0[2], rA1[2], rB1[2], rB3[2];
#pragma unroll
        for (int kc = 0; kc < 2; ++kc) {
            rA0[kc] = load8(x,  aOff[0] + k0 + kc * 32, mode);
            rA1[kc] = load8(x,  aOff[1] + k0 + kc * 32, mode);
            rB1[kc] = load8(W1, bOff    + k0 + kc * 32, mode);
            rB3[kc] = load8(W3, bOff    + k0 + kc * 32, mode);
        }
        __syncthreads();
#pragma unroll
        for (int kc = 0; kc < 2; ++kc) {
            *(s8v*)(lA0 + kc * 512) = rA0[kc];
            *(s8v*)(lA1 + kc * 512) = rA1[kc];
            *(s8v*)(lB1 + kc * 512) = rB1[kc];
            *(s8v*)(lB3 + kc * 512) = rB3[kc];
        }
        __syncthreads();
#pragma unroll
        for (int kc = 0; kc < 2; ++kc) {
            s8v a[4], b1[2], b3[2];
#pragma unroll
            for (int mt = 0; mt < 4; ++mt)
                a[mt] = *(const s8v*)(As + ((wm * 4 + mt) * 2 + kc) * 512 + lane * 8);
#pragma unroll
            for (int nt = 0; nt < 2; ++nt) {
                b1[nt] = *(const s8v*)(B1s + ((wn * 2 + nt) * 2 + kc) * 512 + lane * 8);
                b3[nt] = *(const s8v*)(B3s + ((wn * 2 + nt) * 2 + kc) * 512 + lane * 8);
            }
#pragma unroll
            for (int mt = 0; mt < 4; ++mt)
#pragma unroll
                for (int nt = 0; nt < 2; ++nt) {
                    acc1[mt][nt] = __builtin_amdgcn_mfma_f32_16x16x32_bf16(a[mt], b1[nt], acc1[mt][nt], 0, 0, 0);
                    acc3[mt][nt] = __builtin_amdgcn_mfma_f32_16x16x32_bf16(a[mt], b3[nt], acc3[mt][nt], 0, 0, 0);
                }
        }
    }
    __syncthreads();

    u16* Hs = As;
#pragma unroll
    for (int mt = 0; mt < 4; ++mt)
#pragma unroll
        for (int nt = 0; nt < 2; ++nt)
#pragma unroll
            for (int r = 0; r < 4; ++r) {
                float g = acc1[mt][nt][r];
                float u = acc3[mt][nt][r];
                float h = (g / (1.f + __expf(-g))) * u;
                int row = wm * 64 + mt * 16 + kq * 4 + r;   // C/D: row=(lane>>4)*4+reg
                int col = wn * 32 + nt * 16 + r16;          //      col=lane&15
                Hs[row * 64 + col] = f2b(h);
            }
    __syncthreads();
#pragma unroll
    for (int pass = 0; pass < 4; ++pass) {
        int row = pass * 32 + (tid >> 3);
        int c8  = (tid & 7) * 8;
        *(s8v*)(H + (size_t)(m0 + row) * HID + n0 + c8) = *(const s8v*)(Hs + row * 64 + c8);
    }
}

// ---------------- stage 2: Y = H @ W2^T ----------------
__global__ __launch_bounds__(256) void k_ffn_down(
    const u16* __restrict__ H, const void* __restrict__ w2, const void* __restrict__ sw2,
    const int* __restrict__ pair_tok, const float* __restrict__ pair_coef,
    const int* __restrict__ aoff, float* __restrict__ out_acc, int isShared,
    const int* __restrict__ modep) {
    __shared__ alignas(16) u16 As[BM * BK];
    __shared__ alignas(16) u16 Bs[64 * BK];

    int mode = *modep;
    int m0 = blockIdx.x * BM;
    const void* W2;
    size_t eoff = 0;
    if (isShared) W2 = sw2;
    else {
        int ss = aoff[NE];
        if (m0 >= ss) return;
        int e = 0;
        for (int i = 1; i < NE; ++i) if (m0 >= aoff[i]) e = i;
        W2 = w2; eoff = (size_t)e * DIM * HID;
    }
    int n0 = blockIdx.y * 64;

    int tid = threadIdx.x, wv = tid >> 6, lane = tid & 63;
    int wm = wv >> 1, wn = wv & 1;
    int r16 = lane & 15, kq = lane >> 4;

    const u16* gA[2];
#pragma unroll
    for (int i = 0; i < 2; ++i) {
        int row = m0 + (wv * 2 + i) * 16 + r16;
        gA[i] = H + (size_t)row * HID + kq * 8;
    }
    size_t bOff = eoff + (size_t)(n0 + wv * 16 + r16) * HID + kq * 8;
    u16* lA0 = As + (wv * 2 + 0) * 2 * 512 + lane * 8;
    u16* lA1 = As + (wv * 2 + 1) * 2 * 512 + lane * 8;
    u16* lB  = Bs + wv * 2 * 512 + lane * 8;

    f4v acc[4][2];
#pragma unroll
    for (int a = 0; a < 4; ++a)
#pragma unroll
        for (int b = 0; b < 2; ++b) acc[a][b] = (f4v)0.f;

    for (int kt = 0; kt < HID / BK; ++kt) {   // 43 iters
        int k0 = kt * BK;
        s8v rA0[2], rA1[2], rB[2];
#pragma unroll
        for (int kc = 0; kc < 2; ++kc) {
            rA0[kc] = *(const s8v*)(gA[0] + k0 + kc * 32);
            rA1[kc] = *(const s8v*)(gA[1] + k0 + kc * 32);
            rB[kc]  = load8(W2, bOff + k0 + kc * 32, mode);
        }
        __syncthreads();
#pragma unroll
        for (int kc = 0; kc < 2; ++kc) {
            *(s8v*)(lA0 + kc * 512) = rA0[kc];
            *(s8v*)(lA1 + kc * 512) = rA1[kc];
            *(s8v*)(lB  + kc * 512) = rB[kc];
        }
        __syncthreads();
#pragma unroll
        for (int kc = 0; kc < 2; ++kc) {
            s8v a[4], b[2];
#pragma unroll
            for (int mt = 0; mt < 4; ++mt)
                a[mt] = *(const s8v*)(As + ((wm * 4 + mt) * 2 + kc) * 512 + lane * 8);
#pragma unroll
            for (int nt = 0; nt < 2; ++nt)
                b[nt] = *(const s8v*)(Bs + ((wn * 2 + nt) * 2 + kc) * 512 + lane * 8);
#pragma unroll
            for (int mt = 0; mt < 4; ++mt)
#pragma unroll
                for (int nt = 0; nt < 2; ++nt)
                    acc[mt][nt] = __builtin_amdgcn_mfma_f32_16x16x32_bf16(a[mt], b[nt], acc[mt][nt], 0, 0, 0);
        }
    }

#pragma unroll
    for (int mt = 0; mt < 4; ++mt)
#pragma unroll
        for (int r = 0; r < 4; ++r) {
            int p = m0 + wm * 64 + mt * 16 + kq * 4 + r;
            int tok; float cf;
            if (isShared) { tok = p; cf = 1.0f; }
            else {
                tok = pair_tok[p];
                if (tok < 0) continue;
                cf = pair_coef[p];
            }
            float* dst = out_acc + (size_t)tok * DIM;
#pragma unroll
            for (int nt = 0; nt < 2; ++nt) {
                int col = n0 + wn * 32 + nt * 16 + r16;
                float v = cf * acc[mt][nt][r];
                if (isShared) dst[col] = v;
                else          atomicAdd(dst + col, v);
            }
        }
}

// ---------------- combine: fp32 -> output dtype per mode ----------------
__global__ __launch_bounds__(256) void k_combine(const float* __restrict__ out_acc, void* __restrict__ out,
                                                 const int* __restrict__ modep) {
    int mode = *modep;
    size_t i = (size_t)(blockIdx.x * 256 + threadIdx.x) * 4;   // grid 8192
    f4v v = *(const f4v*)(out_acc + i);
    if (mode == 0) {
        s4v o;
#pragma unroll
        for (int j = 0; j < 4; ++j) o[j] = (short)f2b(v[j]);
        *(s4v*)((u16*)out + i) = o;
    } else {
        *(f4v*)((float*)out + i) = v;
    }
}

extern "C" void kernel_launch(void* const* d_in, const int* in_sizes, int n_in,
                              void* d_out, int out_size, void* d_ws, size_t ws_size,
                              hipStream_t stream) {
    const void* x   = d_in[0];
    const void* gw  = d_in[1];
    const void* w1  = d_in[2];
    const void* w2  = d_in[3];
    const void* w3  = d_in[4];
    const void* sw1 = d_in[5];
    const void* sw2 = d_in[6];
    const void* sw3 = d_in[7];

    char* ws = (char*)d_ws;
    int*   counts    = (int*)(ws + 0);
    int*   aoff      = (int*)(ws + 64);
    int*   cursor    = (int*)(ws + 128);
    int*   mode      = (int*)(ws + 192);
    int*   tok_e     = (int*)(ws + 256);                  //    65,536 B
    float* tok_w     = (float*)(ws + 65792);              //    65,536 B
    int*   pair_tok  = (int*)(ws + 131328);               //    69,632 B
    float* pair_coef = (float*)(ws + 200960);             //    69,632 B
    float* out_acc   = (float*)(ws + 270592);             // 33,554,432 B
    u16*   H         = (u16*)(ws + 33825024);             // 95,813,632 B -> ~123.7 MiB total

    k_detect <<<1,    256, 0, stream>>>((const u16*)x, mode);
    k_init   <<<8192, 256, 0, stream>>>(counts, pair_tok, out_acc);
    k_gate   <<<2048, 256, 0, stream>>>(x, gw, tok_e, tok_w, counts, mode);
    k_scan   <<<1,    64,  0, stream>>>(counts, aoff, cursor);
    k_scatter<<<32,   256, 0, stream>>>(tok_e, tok_w, cursor, pair_tok, pair_coef);

    // phase S: shared expert over all tokens
    k_ffn_up  <<<dim3(T_TOK / BM, HID / 64), 256, 0, stream>>>(x, w1, w3, sw1, sw3, pair_tok, aoff, H, 1, mode);
    k_ffn_down<<<dim3(T_TOK / BM, DIM / 64), 256, 0, stream>>>(H, w2, sw2, pair_tok, pair_coef, aoff, out_acc, 1, mode);
    // phase R: routed experts
    k_ffn_up  <<<dim3(MAXROUTEDMT, HID / 64), 256, 0, stream>>>(x, w1, w3, sw1, sw3, pair_tok, aoff, H, 0, mode);
    k_ffn_down<<<dim3(MAXROUTEDMT, DIM / 64), 256, 0, stream>>>(H, w2, sw2, pair_tok, pair_coef, aoff, out_acc, 0, mode);

    k_combine<<<8192, 256, 0, stream>>>(out_acc, d_out, mode);
}

// Round 4
// 1629.781 us; speedup vs baseline: 1.4822x; 1.4822x over previous
//
#include <hip/hip_runtime.h>
#include <hip/hip_bf16.h>
#include <stdint.h>

// MoE FFN: T=8192 tokens, DIM=1024, HID=2752, E=8, K=2 + shared expert.
// Round 4: inputs confirmed f32 on device. Pre-convert x + all GEMM weights to
// bf16 in workspace once (~45us), so all GEMM K-loops run the pure-bf16
// 16B/lane path (mode=0). Falls back to round-3 behavior if ws_size is too
// small (host-side deterministic branch). Gate/combine still use the detected
// mode against the original buffers.

#define T_TOK 8192
#define DIM   1024
#define HID   2752
#define NE    8
#define BM    128
#define BK    64
#define MAXROUTED   17408
#define MAXROUTEDMT 136

typedef short  s8v  __attribute__((ext_vector_type(8)));
typedef short  s4v  __attribute__((ext_vector_type(4)));
typedef float  f4v  __attribute__((ext_vector_type(4)));
typedef unsigned short u16;

__device__ __forceinline__ float b2f(u16 u) {
    union { unsigned int i; float f; } v; v.i = ((unsigned int)u) << 16; return v.f;
}
__device__ __forceinline__ u16 f2b(float f) {
    union { float f; unsigned int i; } v; v.f = f;
    unsigned int u = v.i;
    return (u16)((u + 0x7fffu + ((u >> 16) & 1u)) >> 16);   // RNE
}

// load 8 consecutive elements (as bf16 bits) from base+elem_off, either dtype
__device__ __forceinline__ s8v load8(const void* base, size_t elem_off, int mode) {
    if (mode == 0) {
        return *(const s8v*)((const u16*)base + elem_off);
    } else {
        const float* f = (const float*)base + elem_off;
        f4v a = *(const f4v*)f;
        f4v b = *(const f4v*)(f + 4);
        s8v r;
        r[0] = (short)f2b(a[0]); r[1] = (short)f2b(a[1]);
        r[2] = (short)f2b(a[2]); r[3] = (short)f2b(a[3]);
        r[4] = (short)f2b(b[0]); r[5] = (short)f2b(b[1]);
        r[6] = (short)f2b(b[2]); r[7] = (short)f2b(b[3]);
        return r;
    }
}

// ---------------- dtype detect: bf16-NaN bit patterns in x ----------------
__global__ void k_detect(const u16* __restrict__ x, int* __restrict__ mode) {
    __shared__ int cnt;
    if (threadIdx.x == 0) cnt = 0;
    __syncthreads();
    int c = 0;
    for (int i = 0; i < 64; ++i) {
        u16 w = x[threadIdx.x * 64 + i];             // 16384-word sample
        if (((w >> 7) & 0xFF) == 0xFF) ++c;          // bf16 exp field all-ones
    }
    atomicAdd(&cnt, c);
    __syncthreads();
    if (threadIdx.x == 0) *mode = (cnt > 4) ? 1 : 0; // f32 sample ~32 hits, bf16 ~0
}

// ---------------- init: zero counts/flag/out_acc, poison pair_tok ----------------
__global__ __launch_bounds__(256) void k_init(int* counts, int* pair_tok, float* out_acc, int* zerop) {
    int i = blockIdx.x * 256 + threadIdx.x;          // grid 8192
    if (i < NE) counts[i] = 0;
    if (i == NE) *zerop = 0;
    if (i < MAXROUTED) pair_tok[i] = -1;
    *(f4v*)(out_acc + (size_t)i * 4) = (f4v)0.f;     // 8,388,608 floats exactly
}

// ---------------- convert: any-dtype -> bf16 ws copy ----------------
__global__ __launch_bounds__(256) void k_convert(u16* __restrict__ dst, const void* __restrict__ src,
                                                 size_t n8, const int* __restrict__ modep) {
    int mode = *modep;
    size_t stride = (size_t)gridDim.x * 256;
    for (size_t i = (size_t)blockIdx.x * 256 + threadIdx.x; i < n8; i += stride) {
        size_t off = i * 8;
        *(s8v*)(dst + off) = load8(src, off, mode);
    }
}

// ---------------- gate: one wave per token (original buffers, real mode) ----------------
__global__ __launch_bounds__(256) void k_gate(const void* __restrict__ x, const void* __restrict__ gw,
                                              int* __restrict__ tok_e, float* __restrict__ tok_w,
                                              int* __restrict__ counts, const int* __restrict__ modep) {
    int mode = *modep;
    int tid  = blockIdx.x * 256 + threadIdx.x;
    int t    = tid >> 6;
    int lane = tid & 63;
    size_t xo = (size_t)t * DIM + lane * 16;
    float xv[16];
    if (mode == 0) {
        s8v a = *(const s8v*)((const u16*)x + xo);
        s8v b = *(const s8v*)((const u16*)x + xo + 8);
#pragma unroll
        for (int j = 0; j < 8; ++j) { xv[j] = b2f((u16)a[j]); xv[8 + j] = b2f((u16)b[j]); }
    } else {
        const float* f = (const float*)x + xo;
#pragma unroll
        for (int j = 0; j < 16; ++j) xv[j] = f[j];
    }
    float acc[NE];
#pragma unroll
    for (int e = 0; e < NE; ++e) {
        size_t go = (size_t)e * DIM + lane * 16;
        float gv[16];
        if (mode == 0) {
            s8v a = *(const s8v*)((const u16*)gw + go);
            s8v b = *(const s8v*)((const u16*)gw + go + 8);
#pragma unroll
            for (int j = 0; j < 8; ++j) { gv[j] = b2f((u16)a[j]); gv[8 + j] = b2f((u16)b[j]); }
        } else {
            const float* f = (const float*)gw + go;
#pragma unroll
            for (int j = 0; j < 16; ++j) gv[j] = f[j];
        }
        float s = 0.f;
#pragma unroll
        for (int j = 0; j < 16; ++j) s += xv[j] * gv[j];
        acc[e] = s;
    }
#pragma unroll
    for (int m = 32; m >= 1; m >>= 1) {
#pragma unroll
        for (int e = 0; e < NE; ++e) acc[e] += __shfl_xor(acc[e], m);
    }
    if (lane == 0) {
        int e0 = 0;
#pragma unroll
        for (int e = 1; e < NE; ++e) if (acc[e] > acc[e0]) e0 = e;
        int e1 = (e0 == 0) ? 1 : 0;
#pragma unroll
        for (int e = 0; e < NE; ++e) if (e != e0 && acc[e] > acc[e1]) e1 = e;
        float w0 = 1.f / (1.f + __expf(acc[e1] - acc[e0]));  // renormalized top-2 softmax
        float w1 = 1.f - w0;
        tok_e[2 * t]     = e0;  tok_e[2 * t + 1] = e1;
        tok_w[2 * t]     = w0;  tok_w[2 * t + 1] = w1;
        atomicAdd(&counts[e0], 1);
        atomicAdd(&counts[e1], 1);
    }
}

// ---------------- scan ----------------
__global__ void k_scan(const int* __restrict__ counts, int* __restrict__ aoff, int* __restrict__ cursor) {
    if (threadIdx.x == 0) {
        int off = 0;
        for (int e = 0; e < NE; ++e) {
            aoff[e] = off; cursor[e] = off;
            off += (counts[e] + BM - 1) & ~(BM - 1);
        }
        aoff[NE] = off;
    }
}

// ---------------- scatter ----------------
__global__ __launch_bounds__(256) void k_scatter(const int* __restrict__ tok_e, const float* __restrict__ tok_w,
                                                 int* __restrict__ cursor,
                                                 int* __restrict__ pair_tok, float* __restrict__ pair_coef) {
    int t = blockIdx.x * 256 + threadIdx.x;   // grid 32
    if (t >= T_TOK) return;
#pragma unroll
    for (int k = 0; k < 2; ++k) {
        int e   = tok_e[2 * t + k];
        float w = tok_w[2 * t + k];
        int pos = atomicAdd(&cursor[e], 1);
        pair_tok[pos]  = t;
        pair_coef[pos] = w;
    }
}

// ---------------- stage 1: H = silu(x@W1^T) * (x@W3^T) ----------------
__global__ __launch_bounds__(256) void k_ffn_up(
    const void* __restrict__ x, const void* __restrict__ w1, const void* __restrict__ w3,
    const void* __restrict__ sw1, const void* __restrict__ sw3,
    const int* __restrict__ pair_tok, const int* __restrict__ aoff,
    u16* __restrict__ H, int isShared, const int* __restrict__ modep) {
    __shared__ alignas(16) u16 As [BM * BK];
    __shared__ alignas(16) u16 B1s[64 * BK];
    __shared__ alignas(16) u16 B3s[64 * BK];

    int mode = *modep;
    int m0 = blockIdx.x * BM;
    const void *W1, *W3;
    size_t eoff = 0;
    if (isShared) { W1 = sw1; W3 = sw3; }
    else {
        int ss = aoff[NE];
        if (m0 >= ss) return;
        int e = 0;
        for (int i = 1; i < NE; ++i) if (m0 >= aoff[i]) e = i;
        W1 = w1; W3 = w3; eoff = (size_t)e * HID * DIM;
    }
    int n0 = blockIdx.y * 64;

    int tid = threadIdx.x, wv = tid >> 6, lane = tid & 63;
    int wm = wv >> 1, wn = wv & 1;
    int r16 = lane & 15, kq = lane >> 4;

    size_t aOff[2];
#pragma unroll
    for (int i = 0; i < 2; ++i) {
        int row = m0 + (wv * 2 + i) * 16 + r16;
        int tok = isShared ? row : pair_tok[row];
        if (tok < 0) tok = 0;
        aOff[i] = (size_t)tok * DIM + kq * 8;
    }
    size_t bOff = eoff + (size_t)(n0 + wv * 16 + r16) * DIM + kq * 8;
    u16* lA0 = As  + (wv * 2 + 0) * 2 * 512 + lane * 8;
    u16* lA1 = As  + (wv * 2 + 1) * 2 * 512 + lane * 8;
    u16* lB1 = B1s + wv * 2 * 512 + lane * 8;
    u16* lB3 = B3s + wv * 2 * 512 + lane * 8;

    f4v acc1[4][2], acc3[4][2];
#pragma unroll
    for (int a = 0; a < 4; ++a)
#pragma unroll
        for (int b = 0; b < 2; ++b) { acc1[a][b] = (f4v)0.f; acc3[a][b] = (f4v)0.f; }

    for (int kt = 0; kt < DIM / BK; ++kt) {   // 16 iters
        int k0 = kt * BK;
        s8v rA0[2], rA1[2], rB1[2], rB3[2];
#pragma unroll
        for (int kc = 0; kc < 2; ++kc) {
            rA0[kc] = load8(x,  aOff[0] + k0 + kc * 32, mode);
            rA1[kc] = load8(x,  aOff[1] + k0 + kc * 32, mode);
            rB1[kc] = load8(W1, bOff    + k0 + kc * 32, mode);
            rB3[kc] = load8(W3, bOff    + k0 + kc * 32, mode);
        }
        __syncthreads();
#pragma unroll
        for (int kc = 0; kc < 2; ++kc) {
            *(s8v*)(lA0 + kc * 512) = rA0[kc];
            *(s8v*)(lA1 + kc * 512) = rA1[kc];
            *(s8v*)(lB1 + kc * 512) = rB1[kc];
            *(s8v*)(lB3 + kc * 512) = rB3[kc];
        }
        __syncthreads();
#pragma unroll
        for (int kc = 0; kc < 2; ++kc) {
            s8v a[4], b1[2], b3[2];
#pragma unroll
            for (int mt = 0; mt < 4; ++mt)
                a[mt] = *(const s8v*)(As + ((wm * 4 + mt) * 2 + kc) * 512 + lane * 8);
#pragma unroll
            for (int nt = 0; nt < 2; ++nt) {
                b1[nt] = *(const s8v*)(B1s + ((wn * 2 + nt) * 2 + kc) * 512 + lane * 8);
                b3[nt] = *(const s8v*)(B3s + ((wn * 2 + nt) * 2 + kc) * 512 + lane * 8);
            }
#pragma unroll
            for (int mt = 0; mt < 4; ++mt)
#pragma unroll
                for (int nt = 0; nt < 2; ++nt) {
                    acc1[mt][nt] = __builtin_amdgcn_mfma_f32_16x16x32_bf16(a[mt], b1[nt], acc1[mt][nt], 0, 0, 0);
                    acc3[mt][nt] = __builtin_amdgcn_mfma_f32_16x16x32_bf16(a[mt], b3[nt], acc3[mt][nt], 0, 0, 0);
                }
        }
    }
    __syncthreads();

    u16* Hs = As;
#pragma unroll
    for (int mt = 0; mt < 4; ++mt)
#pragma unroll
        for (int nt = 0; nt < 2; ++nt)
#pragma unroll
            for (int r = 0; r < 4; ++r) {
                float g = acc1[mt][nt][r];
                float u = acc3[mt][nt][r];
                float h = (g / (1.f + __expf(-g))) * u;
                int row = wm * 64 + mt * 16 + kq * 4 + r;   // C/D: row=(lane>>4)*4+reg
                int col = wn * 32 + nt * 16 + r16;          //      col=lane&15
                Hs[row * 64 + col] = f2b(h);
            }
    __syncthreads();
#pragma unroll
    for (int pass = 0; pass < 4; ++pass) {
        int row = pass * 32 + (tid >> 3);
        int c8  = (tid & 7) * 8;
        *(s8v*)(H + (size_t)(m0 + row) * HID + n0 + c8) = *(const s8v*)(Hs + row * 64 + c8);
    }
}

// ---------------- stage 2: Y = H @ W2^T ----------------
__global__ __launch_bounds__(256) void k_ffn_down(
    const u16* __restrict__ H, const void* __restrict__ w2, const void* __restrict__ sw2,
    const int* __restrict__ pair_tok, const float* __restrict__ pair_coef,
    const int* __restrict__ aoff, float* __restrict__ out_acc, int isShared,
    const int* __restrict__ modep) {
    __shared__ alignas(16) u16 As[BM * BK];
    __shared__ alignas(16) u16 Bs[64 * BK];

    int mode = *modep;
    int m0 = blockIdx.x * BM;
    const void* W2;
    size_t eoff = 0;
    if (isShared) W2 = sw2;
    else {
        int ss = aoff[NE];
        if (m0 >= ss) return;
        int e = 0;
        for (int i = 1; i < NE; ++i) if (m0 >= aoff[i]) e = i;
        W2 = w2; eoff = (size_t)e * DIM * HID;
    }
    int n0 = blockIdx.y * 64;

    int tid = threadIdx.x, wv = tid >> 6, lane = tid & 63;
    int wm = wv >> 1, wn = wv & 1;
    int r16 = lane & 15, kq = lane >> 4;

    const u16* gA[2];
#pragma unroll
    for (int i = 0; i < 2; ++i) {
        int row = m0 + (wv * 2 + i) * 16 + r16;
        gA[i] = H + (size_t)row * HID + kq * 8;
    }
    size_t bOff = eoff + (size_t)(n0 + wv * 16 + r16) * HID + kq * 8;
    u16* lA0 = As + (wv * 2 + 0) * 2 * 512 + lane * 8;
    u16* lA1 = As + (wv * 2 + 1) * 2 * 512 + lane * 8;
    u16* lB  = Bs + wv * 2 * 512 + lane * 8;

    f4v acc[4][2];
#pragma unroll
    for (int a = 0; a < 4; ++a)
#pragma unroll
        for (int b = 0; b < 2; ++b) acc[a][b] = (f4v)0.f;

    for (int kt = 0; kt < HID / BK; ++kt) {   // 43 iters
        int k0 = kt * BK;
        s8v rA0[2], rA1[2], rB[2];
#pragma unroll
        for (int kc = 0; kc < 2; ++kc) {
            rA0[kc] = *(const s8v*)(gA[0] + k0 + kc * 32);
            rA1[kc] = *(const s8v*)(gA[1] + k0 + kc * 32);
            rB[kc]  = load8(W2, bOff + k0 + kc * 32, mode);
        }
        __syncthreads();
#pragma unroll
        for (int kc = 0; kc < 2; ++kc) {
            *(s8v*)(lA0 + kc * 512) = rA0[kc];
            *(s8v*)(lA1 + kc * 512) = rA1[kc];
            *(s8v*)(lB  + kc * 512) = rB[kc];
        }
        __syncthreads();
#pragma unroll
        for (int kc = 0; kc < 2; ++kc) {
            s8v a[4], b[2];
#pragma unroll
            for (int mt = 0; mt < 4; ++mt)
                a[mt] = *(const s8v*)(As + ((wm * 4 + mt) * 2 + kc) * 512 + lane * 8);
#pragma unroll
            for (int nt = 0; nt < 2; ++nt)
                b[nt] = *(const s8v*)(Bs + ((wn * 2 + nt) * 2 + kc) * 512 + lane * 8);
#pragma unroll
            for (int mt = 0; mt < 4; ++mt)
#pragma unroll
                for (int nt = 0; nt < 2; ++nt)
                    acc[mt][nt] = __builtin_amdgcn_mfma_f32_16x16x32_bf16(a[mt], b[nt], acc[mt][nt], 0, 0, 0);
        }
    }

#pragma unroll
    for (int mt = 0; mt < 4; ++mt)
#pragma unroll
        for (int r = 0; r < 4; ++r) {
            int p = m0 + wm * 64 + mt * 16 + kq * 4 + r;
            int tok; float cf;
            if (isShared) { tok = p; cf = 1.0f; }
            else {
                tok = pair_tok[p];
                if (tok < 0) continue;
                cf = pair_coef[p];
            }
            float* dst = out_acc + (size_t)tok * DIM;
#pragma unroll
            for (int nt = 0; nt < 2; ++nt) {
                int col = n0 + wn * 32 + nt * 16 + r16;
                float v = cf * acc[mt][nt][r];
                if (isShared) dst[col] = v;
                else          atomicAdd(dst + col, v);
            }
        }
}

// ---------------- combine: fp32 -> output dtype per mode ----------------
__global__ __launch_bounds__(256) void k_combine(const float* __restrict__ out_acc, void* __restrict__ out,
                                                 const int* __restrict__ modep) {
    int mode = *modep;
    size_t i = (size_t)(blockIdx.x * 256 + threadIdx.x) * 4;   // grid 8192
    f4v v = *(const f4v*)(out_acc + i);
    if (mode == 0) {
        s4v o;
#pragma unroll
        for (int j = 0; j < 4; ++j) o[j] = (short)f2b(v[j]);
        *(s4v*)((u16*)out + i) = o;
    } else {
        *(f4v*)((float*)out + i) = v;
    }
}

extern "C" void kernel_launch(void* const* d_in, const int* in_sizes, int n_in,
                              void* d_out, int out_size, void* d_ws, size_t ws_size,
                              hipStream_t stream) {
    const void* x   = d_in[0];
    const void* gw  = d_in[1];
    const void* w1  = d_in[2];
    const void* w2  = d_in[3];
    const void* w3  = d_in[4];
    const void* sw1 = d_in[5];
    const void* sw2 = d_in[6];
    const void* sw3 = d_in[7];

    char* ws = (char*)d_ws;
    int*   counts    = (int*)(ws + 0);
    int*   aoff      = (int*)(ws + 64);
    int*   cursor    = (int*)(ws + 128);
    int*   mode      = (int*)(ws + 192);
    int*   zerop     = (int*)(ws + 196);
    int*   tok_e     = (int*)(ws + 256);                  //    65,536 B
    float* tok_w     = (float*)(ws + 65792);              //    65,536 B
    int*   pair_tok  = (int*)(ws + 131328);               //    69,632 B
    float* pair_coef = (float*)(ws + 200960);             //    69,632 B
    float* out_acc   = (float*)(ws + 270592);             // 33,554,432 B
    u16*   H         = (u16*)(ws + 33825024);             // 95,813,632 B
    u16*   xb        = (u16*)(ws + 129638656);            // 16,777,216 B
    u16*   w1b       = (u16*)(ws + 146415872);            // 45,088,768 B
    u16*   w3b       = (u16*)(ws + 191504640);            // 45,088,768 B
    u16*   w2b       = (u16*)(ws + 236593408);            // 45,088,768 B
    u16*   sw1b      = (u16*)(ws + 281682176);            //  5,636,096 B
    u16*   sw2b      = (u16*)(ws + 287318272);            //  5,636,096 B
    u16*   sw3b      = (u16*)(ws + 292954368);            //  5,636,096 B
    const size_t NEED = 298590464ull;
    const bool conv = ws_size >= NEED;    // deterministic per-process -> graph-safe

    const size_t XN8  = (size_t)T_TOK * DIM / 8;        // 1,048,576
    const size_t WN8  = (size_t)NE * HID * DIM / 8;     // 2,818,048
    const size_t SWN8 = (size_t)HID * DIM / 8;          //   352,256

    k_detect <<<1,    256, 0, stream>>>((const u16*)x, mode);
    k_init   <<<8192, 256, 0, stream>>>(counts, pair_tok, out_acc, zerop);
    k_gate   <<<2048, 256, 0, stream>>>(x, gw, tok_e, tok_w, counts, mode);
    k_scan   <<<1,    64,  0, stream>>>(counts, aoff, cursor);
    k_scatter<<<32,   256, 0, stream>>>(tok_e, tok_w, cursor, pair_tok, pair_coef);

    const void *gx = x, *gw1 = w1, *gw3 = w3, *gw2 = w2, *gsw1 = sw1, *gsw2 = sw2, *gsw3 = sw3;
    const int* gm = mode;
    if (conv) {
        k_convert<<<2048, 256, 0, stream>>>(xb,   x,   XN8,  mode);
        k_convert<<<2048, 256, 0, stream>>>(w1b,  w1,  WN8,  mode);
        k_convert<<<2048, 256, 0, stream>>>(w3b,  w3,  WN8,  mode);
        k_convert<<<2048, 256, 0, stream>>>(w2b,  w2,  WN8,  mode);
        k_convert<<<2048, 256, 0, stream>>>(sw1b, sw1, SWN8, mode);
        k_convert<<<2048, 256, 0, stream>>>(sw2b, sw2, SWN8, mode);
        k_convert<<<2048, 256, 0, stream>>>(sw3b, sw3, SWN8, mode);
        gx = xb; gw1 = w1b; gw3 = w3b; gw2 = w2b; gsw1 = sw1b; gsw2 = sw2b; gsw3 = sw3b;
        gm = zerop;
    }

    // phase S: shared expert over all tokens
    k_ffn_up  <<<dim3(T_TOK / BM, HID / 64), 256, 0, stream>>>(gx, gw1, gw3, gsw1, gsw3, pair_tok, aoff, H, 1, gm);
    k_ffn_down<<<dim3(T_TOK / BM, DIM / 64), 256, 0, stream>>>(H, gw2, gsw2, pair_tok, pair_coef, aoff, out_acc, 1, gm);
    // phase R: routed experts
    k_ffn_up  <<<dim3(MAXROUTEDMT, HID / 64), 256, 0, stream>>>(gx, gw1, gw3, gsw1, gsw3, pair_tok, aoff, H, 0, gm);
    k_ffn_down<<<dim3(MAXROUTEDMT, DIM / 64), 256, 0, stream>>>(H, gw2, gsw2, pair_tok, pair_coef, aoff, out_acc, 0, gm);

    k_combine<<<8192, 256, 0, stream>>>(out_acc, d_out, mode);
}